// Round 1
// baseline (447.122 us; speedup 1.0000x reference)
//
#include <hip/hip_runtime.h>

#define BATCH 4096
#define NGC   8192
#define NPC   2048

typedef _Float16 f16;
typedef __attribute__((ext_vector_type(8))) _Float16 f16x8;
typedef __attribute__((ext_vector_type(4))) _Float16 f16x4;
typedef __attribute__((ext_vector_type(4))) float   floatx4;

__device__ __forceinline__ float softplus_f(float x) {
    // jax.nn.softplus = log1p(exp(-|x|)) + max(x, 0)
    return fmaxf(x, 0.0f) + log1pf(expf(-fabsf(x)));
}

// ---- prep: g_in f32 -> f16 -------------------------------------------------
__global__ void cvt_g(const float* __restrict__ g, f16* __restrict__ gh) {
    int i = (blockIdx.x * blockDim.x + threadIdx.x) * 4;
    float4 v = *(const float4*)(g + i);
    f16x4 h;
    h[0] = (f16)v.x; h[1] = (f16)v.y; h[2] = (f16)v.z; h[3] = (f16)v.w;
    *(f16x4*)(gh + i) = h;
}

// ---- prep: W = softplus(W_raw) * mask -> f16 -------------------------------
__global__ void cvt_w(const float* __restrict__ W, const float* __restrict__ mask,
                      f16* __restrict__ wh) {
    int i = (blockIdx.x * blockDim.x + threadIdx.x) * 4;
    float4 w = *(const float4*)(W + i);
    float4 m = *(const float4*)(mask + i);
    f16x4 h;
    h[0] = (f16)(softplus_f(w.x) * m.x);
    h[1] = (f16)(softplus_f(w.y) * m.y);
    h[2] = (f16)(softplus_f(w.z) * m.z);
    h[3] = (f16)(softplus_f(w.w) * m.w);
    *(f16x4*)(wh + i) = h;
}

// ---- main GEMM: out[b][p] = relu(sum_k A[b][k]*B[p][k] + bias[p]) ----------
// m97-style: 128x128 C-tile, BK=64, 4 waves (2x2 of 64x64), 16x16x32 f16 MFMA,
// global_load_lds width-16 staging with XOR-swizzled *global* fetch so that
// ds_read_b128 fragment reads are bank-optimal while LDS dst stays linear.
__device__ __forceinline__ void gload_lds16(const f16* g, f16* l) {
    __builtin_amdgcn_global_load_lds((const __attribute__((address_space(1))) void*)g,
                                     (__attribute__((address_space(3))) void*)l,
                                     16, 0, 0);
}

__global__ void gemm_f16(const f16* __restrict__ A, const f16* __restrict__ B,
                         const float* __restrict__ bias, float* __restrict__ out) {
    __shared__ __align__(16) f16 As[128 * 64];   // 16 KB, row stride 64 f16, 16B chunks
    __shared__ __align__(16) f16 Bs[128 * 64];

    const int tid  = threadIdx.x;
    const int lane = tid & 63;
    const int wid  = tid >> 6;
    const int bm0  = blockIdx.y * 128;   // batch
    const int bn0  = blockIdx.x * 128;   // pc
    const int wm   = (wid >> 1) * 64;
    const int wn   = (wid & 1) * 64;
    const int l15  = lane & 15;
    const int lq   = lane >> 4;

    floatx4 acc[4][4] = {};

    for (int kt = 0; kt < NGC / 64; ++kt) {
        const int k0 = kt * 64;
        __syncthreads();               // prior iter's LDS reads done
#pragma unroll
        for (int i = 0; i < 4; ++i) {
            // LDS chunk d (linear, 16B each). It holds global k-group g = (d&7)^(r&7).
            int d = tid + 256 * i;
            int r = d >> 3;
            int g = (d & 7) ^ (r & 7);
            gload_lds16(A + (size_t)(bm0 + r) * NGC + k0 + g * 8, As + d * 8);
            gload_lds16(B + (size_t)(bn0 + r) * NGC + k0 + g * 8, Bs + d * 8);
        }
        __syncthreads();               // compiler inserts vmcnt(0) drain here
#pragma unroll
        for (int ks = 0; ks < 2; ++ks) {
            const int g = ks * 4 + lq; // k-group for this lane's fragment
            f16x8 a[4], b[4];
#pragma unroll
            for (int t = 0; t < 4; ++t) {
                int ra = wm + t * 16 + l15;
                int ca = (ra << 3) | (g ^ (ra & 7));
                a[t] = *(const f16x8*)(As + ca * 8);
                int rb = wn + t * 16 + l15;
                int cb = (rb << 3) | (g ^ (rb & 7));
                b[t] = *(const f16x8*)(Bs + cb * 8);
            }
#pragma unroll
            for (int mt = 0; mt < 4; ++mt)
#pragma unroll
                for (int nt = 0; nt < 4; ++nt)
                    acc[mt][nt] = __builtin_amdgcn_mfma_f32_16x16x32_f16(
                        a[mt], b[nt], acc[mt][nt], 0, 0, 0);
        }
    }

    // epilogue: D layout col=lane&15 (pc), row=(lane>>4)*4+reg (batch)
#pragma unroll
    for (int nt = 0; nt < 4; ++nt) {
        int col  = bn0 + wn + nt * 16 + l15;
        float bv = bias[col];
#pragma unroll
        for (int mt = 0; mt < 4; ++mt) {
#pragma unroll
            for (int r = 0; r < 4; ++r) {
                int row = bm0 + wm + mt * 16 + lq * 4 + r;
                float x = acc[mt][nt][r] + bv;
                out[(size_t)row * NPC + col] = fmaxf(x, 0.0f);
            }
        }
    }
}

// ---- exact fp32 fallback (only if ws too small) ----------------------------
__global__ void naive_kernel(const float* __restrict__ g, const float* __restrict__ W,
                             const float* __restrict__ bias, const float* __restrict__ mask,
                             float* __restrict__ out) {
    int idx = blockIdx.x * 256 + threadIdx.x;   // over BATCH*NPC
    int b = idx / NPC, p = idx % NPC;
    const float* gr = g + (size_t)b * NGC;
    const float* wr = W + (size_t)p * NGC;
    const float* mr = mask + (size_t)p * NGC;
    float acc = bias[p];
    for (int k = 0; k < NGC; ++k) {
        float m = mr[k];
        if (m != 0.0f) acc += gr[k] * softplus_f(wr[k]);
    }
    out[idx] = fmaxf(acc, 0.0f);
}

extern "C" void kernel_launch(void* const* d_in, const int* in_sizes, int n_in,
                              void* d_out, int out_size, void* d_ws, size_t ws_size,
                              hipStream_t stream) {
    const float* g_in  = (const float*)d_in[0];
    const float* W_raw = (const float*)d_in[1];
    const float* b_pc  = (const float*)d_in[2];
    const float* mask  = (const float*)d_in[3];
    float* out = (float*)d_out;

    const size_t gh_elems = (size_t)BATCH * NGC;
    const size_t wh_elems = (size_t)NPC * NGC;
    const size_t need = (gh_elems + wh_elems) * sizeof(f16);   // 96 MB

    if (ws_size >= need) {
        f16* gh = (f16*)d_ws;
        f16* wh = gh + gh_elems;
        cvt_g<<<(int)(gh_elems / 1024), 256, 0, stream>>>(g_in, gh);
        cvt_w<<<(int)(wh_elems / 1024), 256, 0, stream>>>(W_raw, mask, wh);
        dim3 grid(NPC / 128, BATCH / 128);
        gemm_f16<<<grid, 256, 0, stream>>>(gh, wh, b_pc, out);
    } else {
        naive_kernel<<<BATCH * NPC / 256, 256, 0, stream>>>(g_in, W_raw, b_pc, mask, out);
    }
}